// Round 15
// baseline (390.788 us; speedup 1.0000x reference)
//
#include <hip/hip_runtime.h>
#include <hip/hip_fp16.h>

#define DFEAT 64
#define EPSBN 1e-5f
#define SCB 2048      // nodes per scan3 block (256 threads x 8)
#define CHUNK_LG 15
#define CHUNK (1 << CHUNK_LG)   // 32768 edges per chunk
#define RNG 8192      // nodes per partition (one packed 32KB LDS histogram)

// ---------------- LDS-privatized PACKED dual histogram + chunk-local rank ----------------
// one 32KB LDS array: low16 = dst count, high16 = src count. lrank/cnt are u8.
// Grid is (P, C): the 13 partition-blocks of one chunk dispatch ADJACENTLY ->
// the chunk is read once into L2 and shared. 32KB keeps 5 blocks/CU.
__global__ __launch_bounds__(256) void hist2d_kernel(
        const int* __restrict__ src, const int* __restrict__ dst,
        unsigned char* __restrict__ lrank, unsigned char* __restrict__ cnt,
        int* __restrict__ deg_out, int E, int N, int N_pad) {
    __shared__ int h[RNG];
    int tid = threadIdx.x;
    int c = blockIdx.y, p = blockIdx.x;
    int nbeg = p * RNG;
    for (int i = tid; i < RNG; i += 256) h[i] = 0;
    __syncthreads();

    int ebeg = c << CHUNK_LG;
    int eend = min(ebeg + CHUNK, E);
    int nvec = (eend - ebeg) >> 2;              // full int4 groups
    const int4* src4 = (const int4*)(src + ebeg);
    const int4* dst4 = (const int4*)(dst + ebeg);

    int i = tid;
    int4 s4 = make_int4(0, 0, 0, 0), d4 = s4;
    if (i < nvec) { s4 = src4[i]; d4 = dst4[i]; }
    while (i < nvec) {
        int inext = i + 256;
        int4 sn = make_int4(0, 0, 0, 0), dn = sn;
        if (inext < nvec) { sn = src4[inext]; dn = dst4[inext]; }   // prefetch
        int e = ebeg + (i << 2);
        {
            unsigned int so, dof;
            so = (unsigned int)(s4.x - nbeg); if (so < RNG) atomicAdd(&h[so], 0x10000);
            so = (unsigned int)(s4.y - nbeg); if (so < RNG) atomicAdd(&h[so], 0x10000);
            so = (unsigned int)(s4.z - nbeg); if (so < RNG) atomicAdd(&h[so], 0x10000);
            so = (unsigned int)(s4.w - nbeg); if (so < RNG) atomicAdd(&h[so], 0x10000);
            dof = (unsigned int)(d4.x - nbeg);
            if (dof < RNG) lrank[e + 0] = (unsigned char)(atomicAdd(&h[dof], 1) & 0xff);
            dof = (unsigned int)(d4.y - nbeg);
            if (dof < RNG) lrank[e + 1] = (unsigned char)(atomicAdd(&h[dof], 1) & 0xff);
            dof = (unsigned int)(d4.z - nbeg);
            if (dof < RNG) lrank[e + 2] = (unsigned char)(atomicAdd(&h[dof], 1) & 0xff);
            dof = (unsigned int)(d4.w - nbeg);
            if (dof < RNG) lrank[e + 3] = (unsigned char)(atomicAdd(&h[dof], 1) & 0xff);
        }
        s4 = sn; d4 = dn; i = inext;
    }
    for (int e = ebeg + (nvec << 2) + tid; e < eend; e += 256) {
        unsigned int so = (unsigned int)(src[e] - nbeg);
        unsigned int dof = (unsigned int)(dst[e] - nbeg);
        if (so < RNG) atomicAdd(&h[so], 0x10000);
        if (dof < RNG) lrank[e] = (unsigned char)(atomicAdd(&h[dof], 1) & 0xff);
    }
    __syncthreads();

    for (int i2 = tid; i2 < RNG; i2 += 256) {
        int n = nbeg + i2;
        if (n < N) {
            unsigned int v = (unsigned int)h[i2];
            unsigned int vo = v >> 16;
            if (vo) atomicAdd(&deg_out[n], (int)vo);   // contiguous lanes -> batched
            cnt[(size_t)c * N_pad + n] = (unsigned char)(v & 0xffu);
        }
    }
}

// ---------------- fused colscan + xcast (both depend only on hist2d) ----------------
__global__ __launch_bounds__(256) void mid_kernel(
        unsigned int* __restrict__ cnt4, int* __restrict__ deg_in,
        int* __restrict__ bsum, int N, int N_pad4, int C, int NCS,
        const float* __restrict__ x, const int* __restrict__ deg_out,
        unsigned short* __restrict__ x16, int n4) {
    __shared__ int red[256];
    int t = threadIdx.x;
    int b = blockIdx.x;
    if (b >= NCS) {
        // ---- xcast part ----
        int i = (b - NCS) * 256 + t;            // float4 index
        if (i < n4) {
            float coef = rsqrtf((float)max(deg_out[i >> 4], 1));   // 16 f4/row
            float4 v = ((const float4*)x)[i];
            __half2 lo = __floats2half2_rn(v.x * coef, v.y * coef);
            __half2 hi = __floats2half2_rn(v.z * coef, v.w * coef);
            ((__half2*)x16)[2 * i]     = lo;
            ((__half2*)x16)[2 * i + 1] = hi;
        }
        return;
    }
    // ---- colscan part ----
    int g = b * 256 + t;                        // u32 group index (node n0 = 4g)
    int n0 = g << 2;
    int r0 = 0, r1 = 0, r2 = 0, r3 = 0;
    if (n0 < N) {
        for (int c = 0; c < C; ++c) {
            size_t idx = (size_t)c * N_pad4 + g;
            unsigned int v = cnt4[idx];
            cnt4[idx] = (unsigned int)r0 | ((unsigned int)r1 << 8) |
                        ((unsigned int)r2 << 16) | ((unsigned int)r3 << 24);
            r0 += (int)(v & 0xffu);
            r1 += (int)((v >> 8) & 0xffu);
            r2 += (int)((v >> 16) & 0xffu);
            r3 += (int)(v >> 24);
        }
    }
    int tot = 0;
    if (n0     < N) { deg_in[n0]     = r0; tot += r0; }
    if (n0 + 1 < N) { deg_in[n0 + 1] = r1; tot += r1; }
    if (n0 + 2 < N) { deg_in[n0 + 2] = r2; tot += r2; }
    if (n0 + 3 < N) { deg_in[n0 + 3] = r3; tot += r3; }
    red[t] = tot;
    __syncthreads();
    for (int d = 128; d > 0; d >>= 1) {
        if (t < d) red[t] += red[t + d];
        __syncthreads();
    }
    if (t == 0) bsum[b] = red[0];
}

// ---------------- full exclusive scan -> row_start (scan2 folded in) ----------------
__global__ void scan3_kernel(const int* __restrict__ deg, const int* __restrict__ bsum,
                             int* __restrict__ row_start, int N, int E) {
    __shared__ int sc[256];
    __shared__ int base_sh;
    int t = threadIdx.x;
    int limit = blockIdx.x * (SCB / 1024);   // colscan blocks preceding this block
    if (t < 64) {
        int s = 0;
        for (int j = t; j < limit; j += 64) s += bsum[j];
        #pragma unroll
        for (int off = 32; off > 0; off >>= 1) s += __shfl_down(s, off);
        if (t == 0) base_sh = s;
    }
    int base = blockIdx.x * SCB + t * 8;
    int v[8], ex[8];
    int s = 0;
    #pragma unroll
    for (int j = 0; j < 8; ++j) {
        int idx = base + j;
        v[j] = (idx < N) ? deg[idx] : 0;
        ex[j] = s;
        s += v[j];
    }
    sc[t] = s;
    __syncthreads();                          // also orders base_sh write
    for (int d = 1; d < 256; d <<= 1) {
        int vv = (t >= d) ? sc[t - d] : 0;
        __syncthreads();
        sc[t] += vv;
        __syncthreads();
    }
    int toff = sc[t] - s + base_sh;
    #pragma unroll
    for (int j = 0; j < 8; ++j) {
        int idx = base + j;
        if (idx < N) row_start[idx] = toff + ex[j];
    }
    if (blockIdx.x == 0 && t == 0) row_start[N] = E;
}

// ---------------- place edges, 4/thread: slot = row_start[d] + pref + lrank ----------------
__global__ __launch_bounds__(256) void fill_kernel(
        const int* __restrict__ src, const int* __restrict__ dst,
        const unsigned char* __restrict__ lrank,
        const unsigned char* __restrict__ cnt,
        const int* __restrict__ row_start,
        int* __restrict__ epack, int E, int N_pad) {
    int i = blockIdx.x * 256 + threadIdx.x;   // int4 group index
    int nvec = E >> 2;
    if (i < nvec) {
        int4 s4 = ((const int4*)src)[i];
        int4 d4 = ((const int4*)dst)[i];
        uchar4 r4 = ((const uchar4*)lrank)[i];
        size_t cb = (size_t)((i << 2) >> CHUNK_LG) * N_pad;
        epack[row_start[d4.x] + (int)cnt[cb + d4.x] + (int)r4.x] = s4.x;
        epack[row_start[d4.y] + (int)cnt[cb + d4.y] + (int)r4.y] = s4.y;
        epack[row_start[d4.z] + (int)cnt[cb + d4.z] + (int)r4.z] = s4.z;
        epack[row_start[d4.w] + (int)cnt[cb + d4.w] + (int)r4.w] = s4.w;
    }
    int e = (nvec << 2) + i;                  // <=3 tail edges
    if (e < E && i < 4) {
        int d = dst[e];
        size_t cb = (size_t)(e >> CHUNK_LG) * N_pad;
        epack[row_start[d] + (int)cnt[cb + d] + (int)lrank[e]] = src[e];
    }
}

// ---------------- fused SpMM + GEMM + BN partials: 4 rows per wave, INTERLEAVED ----------------
// r14 post-mortem: spmm latency-bound (BW 20%, VALU 51% -- neither pipe half
// used). The 4 rows were processed SERIALLY: one dependent chain {s_load
// batch -> gather -> consume} with only 8 gathers in flight. Now the rows
// advance in LOCKSTEP batches: phase 1 issues all active rows' epack s_loads,
// phase 2 issues all gathers (up to 32 in flight), phase 3 accumulates.
// Guards are wave-uniform (scalar branches). Unlike r13's within-row
// pipelining (same chain + extra VALU -> regressed), these chains are
// INDEPENDENT -- pure added memory-level parallelism.
__global__ __launch_bounds__(256, 8) void spmm_gemm_kernel(
        const unsigned short* __restrict__ x16, const int* __restrict__ row_start,
        const int* __restrict__ epack, const float* __restrict__ W,
        const float* __restrict__ bvec, float* __restrict__ y,
        float* __restrict__ partial, int N) {
    __shared__ float Wl[DFEAT * DFEAT];
    __shared__ float red_s[4][DFEAT];
    __shared__ float red_q[4][DFEAT];
    int tid = threadIdx.x;
    {
        const float4* W4 = (const float4*)W;
        float4* Wl4 = (float4*)Wl;
        #pragma unroll
        for (int j = 0; j < 4; ++j) Wl4[tid + 256 * j] = W4[tid + 256 * j];
    }
    __syncthreads();

    int lane = tid & 63;
    int w = tid >> 6;
    int r0 = blockIdx.x * 16 + w * 4;
    float bv = bvec[lane];
    const __half* xh = (const __half*)x16;

    int begq[4], degq[4];
    #pragma unroll
    for (int q = 0; q < 4; ++q) {
        int r = r0 + q;
        int b_ = 0, e_ = 0;
        if (r < N) {
            b_ = __builtin_amdgcn_readfirstlane(row_start[r]);
            e_ = __builtin_amdgcn_readfirstlane(row_start[r + 1]);
        }
        begq[q] = b_;
        degq[q] = e_ - b_;
    }
    float aq[4] = {0.f, 0.f, 0.f, 0.f};
    int nb[4];
    #pragma unroll
    for (int q = 0; q < 4; ++q) nb[q] = degq[q] >> 3;   // full 8-batches
    int maxb = max(max(nb[0], nb[1]), max(nb[2], nb[3]));

    for (int b = 0; b < maxb; ++b) {
        int j = b << 3;
        int p[4][8];
        // phase 1: issue all rows' epack scalar loads (uniform branches)
        #pragma unroll
        for (int q = 0; q < 4; ++q) {
            if (b < nb[q]) {
                const int* ep = epack + begq[q] + j;
                #pragma unroll
                for (int u = 0; u < 8; ++u) p[q][u] = ep[u];
            }
        }
        // phase 2: issue all gathers (up to 32 in flight)
        float v[4][8];
        #pragma unroll
        for (int q = 0; q < 4; ++q) {
            if (b < nb[q]) {
                #pragma unroll
                for (int u = 0; u < 8; ++u)
                    v[q][u] = __half2float(xh[(size_t)p[q][u] * DFEAT + lane]);
            }
        }
        // phase 3: accumulate
        #pragma unroll
        for (int q = 0; q < 4; ++q) {
            if (b < nb[q]) {
                aq[q] += ((v[q][0] + v[q][1]) + (v[q][2] + v[q][3]))
                       + ((v[q][4] + v[q][5]) + (v[q][6] + v[q][7]));
            }
        }
    }
    // per-row tails (<8 edges each)
    #pragma unroll
    for (int q = 0; q < 4; ++q) {
        const int* ep = epack + begq[q];
        for (int j = nb[q] << 3; j < degq[q]; ++j)
            aq[q] += __half2float(xh[(size_t)ep[j] * DFEAT + lane]);
        aq[q] *= rsqrtf((float)max(degq[q], 1));   // norm_dst
    }

    // ---- in-wave GEMM tail, W read shared by 4 rows
    float yo0 = 0.f, yo1 = 0.f, yo2 = 0.f, yo3 = 0.f;
    int ai0 = __float_as_int(aq[0]);
    int ai1 = __float_as_int(aq[1]);
    int ai2 = __float_as_int(aq[2]);
    int ai3 = __float_as_int(aq[3]);
    #pragma unroll 8
    for (int k = 0; k < DFEAT; ++k) {
        float wk = Wl[k * DFEAT + lane];     // conflict-free, 1 read / 4 rows
        yo0 = fmaf(__int_as_float(__builtin_amdgcn_readlane(ai0, k)), wk, yo0);
        yo1 = fmaf(__int_as_float(__builtin_amdgcn_readlane(ai1, k)), wk, yo1);
        yo2 = fmaf(__int_as_float(__builtin_amdgcn_readlane(ai2, k)), wk, yo2);
        yo3 = fmaf(__int_as_float(__builtin_amdgcn_readlane(ai3, k)), wk, yo3);
    }

    float yq[4] = {yo0, yo1, yo2, yo3};
    float ps = 0.f, pq = 0.f;                // column (=lane) partial stats
    #pragma unroll
    for (int q = 0; q < 4; ++q) {
        int r = r0 + q;
        if (r < N) {
            float yv = bv + yq[q];
            y[(size_t)r * DFEAT + lane] = yv;
            ps += yv;
            pq = fmaf(yv, yv, pq);
        }
    }

    red_s[w][lane] = ps;
    red_q[w][lane] = pq;
    __syncthreads();
    if (w == 0) {
        float s = red_s[0][lane] + red_s[1][lane] + red_s[2][lane] + red_s[3][lane];
        float q2 = red_q[0][lane] + red_q[1][lane] + red_q[2][lane] + red_q[3][lane];
        float* p = partial + (size_t)blockIdx.x * 128;
        p[lane] = s;
        p[64 + lane] = q2;
    }
}

// ---------------- BN stats finalize: contiguous spans, 4-way ILP ----------------
__global__ void bnstat2_kernel(const float* __restrict__ partial,
                               float* __restrict__ sums, int G) {
    int j = threadIdx.x;                      // 0..127 (sums||sumsq column)
    int span = (G + (int)gridDim.x - 1) / (int)gridDim.x;
    int g0 = blockIdx.x * span;
    int g1 = min(G, g0 + span);
    float s0 = 0.f, s1 = 0.f, s2 = 0.f, s3 = 0.f;
    int g = g0;
    for (; g + 4 <= g1; g += 4) {
        s0 += partial[(size_t)(g + 0) * 128 + j];
        s1 += partial[(size_t)(g + 1) * 128 + j];
        s2 += partial[(size_t)(g + 2) * 128 + j];
        s3 += partial[(size_t)(g + 3) * 128 + j];
    }
    for (; g < g1; ++g) s0 += partial[(size_t)g * 128 + j];
    float s = (s0 + s1) + (s2 + s3);
    atomicAdd(&sums[j], s);                   // sums||sumsq contiguous
}

// ---------------- BN (batch stats) + ReLU + residual, float4, in place on y ----------------
__global__ void bn_relu_res_kernel(const float* __restrict__ x,
                                   const float* __restrict__ sums,
                                   const float* __restrict__ sumsq,
                                   const float* __restrict__ gamma,
                                   const float* __restrict__ beta,
                                   float* __restrict__ y, int n4, float inv_n) {
    int i = blockIdx.x * blockDim.x + threadIdx.x;   // float4 index
    if (i < n4) {
        int c0 = (i << 2) & (DFEAT - 1);
        float4 yv = ((const float4*)y)[i];
        float4 xv = ((const float4*)x)[i];
        float o[4] = {yv.x, yv.y, yv.z, yv.w};
        float xi[4] = {xv.x, xv.y, xv.z, xv.w};
        #pragma unroll
        for (int k = 0; k < 4; ++k) {
            int c = c0 + k;
            float mean = sums[c] * inv_n;
            float var = sumsq[c] * inv_n - mean * mean;
            float inv = rsqrtf(var + EPSBN);
            float v = (o[k] - mean) * inv * gamma[c] + beta[c];
            o[k] = xi[k] + fmaxf(v, 0.f);
        }
        ((float4*)y)[i] = make_float4(o[0], o[1], o[2], o[3]);
    }
}

extern "C" void kernel_launch(void* const* d_in, const int* in_sizes, int n_in,
                              void* d_out, int out_size, void* d_ws, size_t ws_size,
                              hipStream_t stream) {
    const float* x     = (const float*)d_in[0];
    const int*   src   = (const int*)d_in[1];
    const int*   dst   = (const int*)d_in[2];
    const float* W     = (const float*)d_in[3];
    const float* bvec  = (const float*)d_in[4];
    const float* gamma = (const float*)d_in[5];
    const float* beta  = (const float*)d_in[6];
    float* out = (float*)d_out;   // y, written once by fused spmm+gemm

    const int n_nodes = in_sizes[0] / DFEAT;
    const int E = in_sizes[1];
    const int NB = (n_nodes + SCB - 1) / SCB;           // scan3 blocks (49)
    const int C = (E + CHUNK - 1) >> CHUNK_LG;          // edge chunks (49)
    const int P = (n_nodes + RNG - 1) / RNG;            // node partitions (13)
    const int N_pad = P * RNG;                          // 106496 (div by 4)
    const size_t tbl = (size_t)C * N_pad;               // 5.2MB u8 cnt table

    // ws: epack (E int, 6.4MB) | x16 (N*64 fp16, 12.8MB) | lrank (E u8, 1.6MB) |
    //     cnt (C*N_pad u8, 5.2MB) | deg_out N | sums 64 | sumsq 64 | deg_in N |
    //     row_start N+1 | bsum 512     (total ~27.3MB)
    // partial aliases cnt (dead after fill): grid_sg*512B = 3.2MB <= 5.2MB.
    char* wsb = (char*)d_ws;
    int* epack            = (int*)wsb;
    unsigned short* x16   = (unsigned short*)(wsb + (size_t)E * 4);
    unsigned char* lrank  = (unsigned char*)((char*)x16 + (size_t)n_nodes * DFEAT * 2);
    size_t lrank_bytes    = ((size_t)E + 15) & ~(size_t)15;
    unsigned char* cnt    = lrank + lrank_bytes;
    int*  deg_out_i  = (int*)(cnt + tbl);
    float* sums      = (float*)(deg_out_i + n_nodes);
    float* sumsq     = sums + DFEAT;
    int*  deg_in_i   = (int*)(sumsq + DFEAT);
    int*  row_start  = deg_in_i + n_nodes;
    int*  bsum       = row_start + n_nodes + 1;         // 100 used, 512 reserved
    float* partial   = (float*)cnt;

    // zero: deg_out + sums + sumsq (contiguous; bnstat2 atomic-accumulates).
    hipMemsetAsync(deg_out_i, 0, ((size_t)n_nodes + 2 * DFEAT) * sizeof(int), stream);

    hist2d_kernel<<<dim3(P, C), 256, 0, stream>>>(src, dst, lrank, cnt, deg_out_i,
                                                  E, n_nodes, N_pad);

    int n4 = n_nodes * DFEAT / 4;
    int ngroups = (n_nodes + 3) / 4;                    // u32 groups of 4 nodes
    int NCS = (ngroups + 255) / 256;                    // colscan blocks (100)
    int NXB = (n4 + 255) / 256;                         // xcast blocks (1563)
    mid_kernel<<<NCS + NXB, 256, 0, stream>>>(
        (unsigned int*)cnt, deg_in_i, bsum, n_nodes, N_pad / 4, C, NCS,
        x, deg_out_i, x16, n4);

    scan3_kernel<<<NB, 256, 0, stream>>>(deg_in_i, bsum, row_start, n_nodes, E);

    int nvec = E >> 2;
    fill_kernel<<<(nvec + 255) / 256, 256, 0, stream>>>(src, dst, lrank, cnt,
                                                        row_start, epack, E, N_pad);

    int grid_sg = (n_nodes + 15) / 16;
    spmm_gemm_kernel<<<grid_sg, 256, 0, stream>>>(x16, row_start, epack,
                                                  W, bvec, out, partial, n_nodes);

    bnstat2_kernel<<<64, 128, 0, stream>>>(partial, sums, grid_sg);

    bn_relu_res_kernel<<<(n4 + 255) / 256, 256, 0, stream>>>(
        x, sums, sumsq, gamma, beta, out, n4, 1.0f / (float)n_nodes);
}

// Round 17
// 280.739 us; speedup vs baseline: 1.3920x; 1.3920x over previous
//
#include <hip/hip_runtime.h>
#include <hip/hip_fp16.h>

#define DFEAT 64
#define EPSBN 1e-5f
#define SCB 2048      // nodes per scan3 block (256 threads x 8)
#define CHUNK_LG 15
#define CHUNK (1 << CHUNK_LG)   // 32768 edges per chunk
#define RNG 8192      // nodes per partition (one packed 32KB LDS histogram)

// ---------------- LDS-privatized PACKED dual histogram + chunk-local rank ----------------
// one 32KB LDS array: low16 = dst count, high16 = src count. lrank/cnt are u8.
// Grid is (P, C): the 13 partition-blocks of one chunk dispatch ADJACENTLY ->
// the chunk is read once into L2 and shared. 32KB keeps 5 blocks/CU.
__global__ __launch_bounds__(256) void hist2d_kernel(
        const int* __restrict__ src, const int* __restrict__ dst,
        unsigned char* __restrict__ lrank, unsigned char* __restrict__ cnt,
        int* __restrict__ deg_out, int E, int N, int N_pad) {
    __shared__ int h[RNG];
    int tid = threadIdx.x;
    int c = blockIdx.y, p = blockIdx.x;
    int nbeg = p * RNG;
    for (int i = tid; i < RNG; i += 256) h[i] = 0;
    __syncthreads();

    int ebeg = c << CHUNK_LG;
    int eend = min(ebeg + CHUNK, E);
    int nvec = (eend - ebeg) >> 2;              // full int4 groups
    const int4* src4 = (const int4*)(src + ebeg);
    const int4* dst4 = (const int4*)(dst + ebeg);

    int i = tid;
    int4 s4 = make_int4(0, 0, 0, 0), d4 = s4;
    if (i < nvec) { s4 = src4[i]; d4 = dst4[i]; }
    while (i < nvec) {
        int inext = i + 256;
        int4 sn = make_int4(0, 0, 0, 0), dn = sn;
        if (inext < nvec) { sn = src4[inext]; dn = dst4[inext]; }   // prefetch
        int e = ebeg + (i << 2);
        {
            unsigned int so, dof;
            so = (unsigned int)(s4.x - nbeg); if (so < RNG) atomicAdd(&h[so], 0x10000);
            so = (unsigned int)(s4.y - nbeg); if (so < RNG) atomicAdd(&h[so], 0x10000);
            so = (unsigned int)(s4.z - nbeg); if (so < RNG) atomicAdd(&h[so], 0x10000);
            so = (unsigned int)(s4.w - nbeg); if (so < RNG) atomicAdd(&h[so], 0x10000);
            dof = (unsigned int)(d4.x - nbeg);
            if (dof < RNG) lrank[e + 0] = (unsigned char)(atomicAdd(&h[dof], 1) & 0xff);
            dof = (unsigned int)(d4.y - nbeg);
            if (dof < RNG) lrank[e + 1] = (unsigned char)(atomicAdd(&h[dof], 1) & 0xff);
            dof = (unsigned int)(d4.z - nbeg);
            if (dof < RNG) lrank[e + 2] = (unsigned char)(atomicAdd(&h[dof], 1) & 0xff);
            dof = (unsigned int)(d4.w - nbeg);
            if (dof < RNG) lrank[e + 3] = (unsigned char)(atomicAdd(&h[dof], 1) & 0xff);
        }
        s4 = sn; d4 = dn; i = inext;
    }
    for (int e = ebeg + (nvec << 2) + tid; e < eend; e += 256) {
        unsigned int so = (unsigned int)(src[e] - nbeg);
        unsigned int dof = (unsigned int)(dst[e] - nbeg);
        if (so < RNG) atomicAdd(&h[so], 0x10000);
        if (dof < RNG) lrank[e] = (unsigned char)(atomicAdd(&h[dof], 1) & 0xff);
    }
    __syncthreads();

    for (int i2 = tid; i2 < RNG; i2 += 256) {
        int n = nbeg + i2;
        if (n < N) {
            unsigned int v = (unsigned int)h[i2];
            unsigned int vo = v >> 16;
            if (vo) atomicAdd(&deg_out[n], (int)vo);   // contiguous lanes -> batched
            cnt[(size_t)c * N_pad + n] = (unsigned char)(v & 0xffu);
        }
    }
}

// ---------------- fused colscan + xcast (both depend only on hist2d) ----------------
__global__ __launch_bounds__(256) void mid_kernel(
        unsigned int* __restrict__ cnt4, int* __restrict__ deg_in,
        int* __restrict__ bsum, int N, int N_pad4, int C, int NCS,
        const float* __restrict__ x, const int* __restrict__ deg_out,
        unsigned short* __restrict__ x16, int n4) {
    __shared__ int red[256];
    int t = threadIdx.x;
    int b = blockIdx.x;
    if (b >= NCS) {
        // ---- xcast part ----
        int i = (b - NCS) * 256 + t;            // float4 index
        if (i < n4) {
            float coef = rsqrtf((float)max(deg_out[i >> 4], 1));   // 16 f4/row
            float4 v = ((const float4*)x)[i];
            __half2 lo = __floats2half2_rn(v.x * coef, v.y * coef);
            __half2 hi = __floats2half2_rn(v.z * coef, v.w * coef);
            ((__half2*)x16)[2 * i]     = lo;
            ((__half2*)x16)[2 * i + 1] = hi;
        }
        return;
    }
    // ---- colscan part ----
    int g = b * 256 + t;                        // u32 group index (node n0 = 4g)
    int n0 = g << 2;
    int r0 = 0, r1 = 0, r2 = 0, r3 = 0;
    if (n0 < N) {
        for (int c = 0; c < C; ++c) {
            size_t idx = (size_t)c * N_pad4 + g;
            unsigned int v = cnt4[idx];
            cnt4[idx] = (unsigned int)r0 | ((unsigned int)r1 << 8) |
                        ((unsigned int)r2 << 16) | ((unsigned int)r3 << 24);
            r0 += (int)(v & 0xffu);
            r1 += (int)((v >> 8) & 0xffu);
            r2 += (int)((v >> 16) & 0xffu);
            r3 += (int)(v >> 24);
        }
    }
    int tot = 0;
    if (n0     < N) { deg_in[n0]     = r0; tot += r0; }
    if (n0 + 1 < N) { deg_in[n0 + 1] = r1; tot += r1; }
    if (n0 + 2 < N) { deg_in[n0 + 2] = r2; tot += r2; }
    if (n0 + 3 < N) { deg_in[n0 + 3] = r3; tot += r3; }
    red[t] = tot;
    __syncthreads();
    for (int d = 128; d > 0; d >>= 1) {
        if (t < d) red[t] += red[t + d];
        __syncthreads();
    }
    if (t == 0) bsum[b] = red[0];
}

// ---------------- full exclusive scan -> row_start (scan2 folded in) ----------------
__global__ void scan3_kernel(const int* __restrict__ deg, const int* __restrict__ bsum,
                             int* __restrict__ row_start, int N, int E) {
    __shared__ int sc[256];
    __shared__ int base_sh;
    int t = threadIdx.x;
    int limit = blockIdx.x * (SCB / 1024);   // colscan blocks preceding this block
    if (t < 64) {
        int s = 0;
        for (int j = t; j < limit; j += 64) s += bsum[j];
        #pragma unroll
        for (int off = 32; off > 0; off >>= 1) s += __shfl_down(s, off);
        if (t == 0) base_sh = s;
    }
    int base = blockIdx.x * SCB + t * 8;
    int v[8], ex[8];
    int s = 0;
    #pragma unroll
    for (int j = 0; j < 8; ++j) {
        int idx = base + j;
        v[j] = (idx < N) ? deg[idx] : 0;
        ex[j] = s;
        s += v[j];
    }
    sc[t] = s;
    __syncthreads();                          // also orders base_sh write
    for (int d = 1; d < 256; d <<= 1) {
        int vv = (t >= d) ? sc[t - d] : 0;
        __syncthreads();
        sc[t] += vv;
        __syncthreads();
    }
    int toff = sc[t] - s + base_sh;
    #pragma unroll
    for (int j = 0; j < 8; ++j) {
        int idx = base + j;
        if (idx < N) row_start[idx] = toff + ex[j];
    }
    if (blockIdx.x == 0 && t == 0) row_start[N] = E;
}

// ---------------- place edges, 4/thread: slot = row_start[d] + pref + lrank ----------------
__global__ __launch_bounds__(256) void fill_kernel(
        const int* __restrict__ src, const int* __restrict__ dst,
        const unsigned char* __restrict__ lrank,
        const unsigned char* __restrict__ cnt,
        const int* __restrict__ row_start,
        int* __restrict__ epack, int E, int N_pad) {
    int i = blockIdx.x * 256 + threadIdx.x;   // int4 group index
    int nvec = E >> 2;
    if (i < nvec) {
        int4 s4 = ((const int4*)src)[i];
        int4 d4 = ((const int4*)dst)[i];
        uchar4 r4 = ((const uchar4*)lrank)[i];
        size_t cb = (size_t)((i << 2) >> CHUNK_LG) * N_pad;
        epack[row_start[d4.x] + (int)cnt[cb + d4.x] + (int)r4.x] = s4.x;
        epack[row_start[d4.y] + (int)cnt[cb + d4.y] + (int)r4.y] = s4.y;
        epack[row_start[d4.z] + (int)cnt[cb + d4.z] + (int)r4.z] = s4.z;
        epack[row_start[d4.w] + (int)cnt[cb + d4.w] + (int)r4.w] = s4.w;
    }
    int e = (nvec << 2) + i;                  // <=3 tail edges
    if (e < E && i < 4) {
        int d = dst[e];
        size_t cb = (size_t)(e >> CHUNK_LG) * N_pad;
        epack[row_start[d] + (int)cnt[cb + d] + (int)lrank[e]] = src[e];
    }
}

// ---------------- fused SpMM + GEMM + BN partials: PAIRWISE row lockstep ----------------
// r15/r16 post-mortems: (a) conditional arrays spill to scratch (WRITE 28->
// 337MB); (b) cooperative tail fusion fails. This keeps r14's proven serial
// loop for remainders but processes row PAIRS (0,1) and (2,3) in lockstep
// over their COMMON batch prefix with UNCONDITIONAL scalar-named loads:
// epack values come from wave-uniform pointers (SGPRs, zero VGPR cost); only
// the 16 gather floats are VGPRs -> no spill possible. Doubles gathers in
// flight (8->16) for ~65% of edges (Poisson(16): E[min] ~13 of ~19).
__global__ __launch_bounds__(256, 8) void spmm_gemm_kernel(
        const unsigned short* __restrict__ x16, const int* __restrict__ row_start,
        const int* __restrict__ epack, const float* __restrict__ W,
        const float* __restrict__ bvec, float* __restrict__ y,
        float* __restrict__ partial, int N) {
    __shared__ float Wl[DFEAT * DFEAT];
    __shared__ float red_s[4][DFEAT];
    __shared__ float red_q[4][DFEAT];
    int tid = threadIdx.x;
    {
        const float4* W4 = (const float4*)W;
        float4* Wl4 = (float4*)Wl;
        #pragma unroll
        for (int j = 0; j < 4; ++j) Wl4[tid + 256 * j] = W4[tid + 256 * j];
    }
    __syncthreads();

    int lane = tid & 63;
    int w = tid >> 6;
    int r0 = blockIdx.x * 16 + w * 4;
    float bv = bvec[lane];
    const __half* xh = (const __half*)x16;

    int begq[4], degq[4];
    #pragma unroll
    for (int q = 0; q < 4; ++q) {
        int r = r0 + q;
        int b_ = 0, e_ = 0;
        if (r < N) {
            b_ = __builtin_amdgcn_readfirstlane(row_start[r]);
            e_ = __builtin_amdgcn_readfirstlane(row_start[r + 1]);
        }
        begq[q] = b_;
        degq[q] = e_ - b_;
    }

    float aq[4];
    #pragma unroll
    for (int pr = 0; pr < 2; ++pr) {
        int qa = pr * 2, qb = qa + 1;
        const int* epa = epack + begq[qa];
        const int* epb = epack + begq[qb];
        int da = degq[qa], db = degq[qb];
        int cmn = min(da, db) & ~7;           // common full-batch prefix (edges)
        float aa = 0.f, ab = 0.f;
        int j = 0;
        for (; j < cmn; j += 8) {
            // phase 1: both rows' epack scalar loads (unconditional, SGPRs)
            int a0 = epa[j + 0], a1 = epa[j + 1], a2 = epa[j + 2], a3 = epa[j + 3];
            int a4 = epa[j + 4], a5 = epa[j + 5], a6 = epa[j + 6], a7 = epa[j + 7];
            int b0 = epb[j + 0], b1 = epb[j + 1], b2 = epb[j + 2], b3 = epb[j + 3];
            int b4 = epb[j + 4], b5 = epb[j + 5], b6 = epb[j + 6], b7 = epb[j + 7];
            // phase 2: 16 gathers in flight
            float u0 = __half2float(xh[(size_t)a0 * DFEAT + lane]);
            float u1 = __half2float(xh[(size_t)a1 * DFEAT + lane]);
            float u2 = __half2float(xh[(size_t)a2 * DFEAT + lane]);
            float u3 = __half2float(xh[(size_t)a3 * DFEAT + lane]);
            float u4 = __half2float(xh[(size_t)a4 * DFEAT + lane]);
            float u5 = __half2float(xh[(size_t)a5 * DFEAT + lane]);
            float u6 = __half2float(xh[(size_t)a6 * DFEAT + lane]);
            float u7 = __half2float(xh[(size_t)a7 * DFEAT + lane]);
            float g0 = __half2float(xh[(size_t)b0 * DFEAT + lane]);
            float g1 = __half2float(xh[(size_t)b1 * DFEAT + lane]);
            float g2 = __half2float(xh[(size_t)b2 * DFEAT + lane]);
            float g3 = __half2float(xh[(size_t)b3 * DFEAT + lane]);
            float g4 = __half2float(xh[(size_t)b4 * DFEAT + lane]);
            float g5 = __half2float(xh[(size_t)b5 * DFEAT + lane]);
            float g6 = __half2float(xh[(size_t)b6 * DFEAT + lane]);
            float g7 = __half2float(xh[(size_t)b7 * DFEAT + lane]);
            aa += ((u0 + u1) + (u2 + u3)) + ((u4 + u5) + (u6 + u7));
            ab += ((g0 + g1) + (g2 + g3)) + ((g4 + g5) + (g6 + g7));
        }
        // row a remainder: full batches then tail (r14-proven serial form)
        int ja = j;
        for (; ja + 8 <= da; ja += 8) {
            int p0 = epa[ja + 0], p1 = epa[ja + 1], p2 = epa[ja + 2], p3 = epa[ja + 3];
            int p4 = epa[ja + 4], p5 = epa[ja + 5], p6 = epa[ja + 6], p7 = epa[ja + 7];
            float u0 = __half2float(xh[(size_t)p0 * DFEAT + lane]);
            float u1 = __half2float(xh[(size_t)p1 * DFEAT + lane]);
            float u2 = __half2float(xh[(size_t)p2 * DFEAT + lane]);
            float u3 = __half2float(xh[(size_t)p3 * DFEAT + lane]);
            float u4 = __half2float(xh[(size_t)p4 * DFEAT + lane]);
            float u5 = __half2float(xh[(size_t)p5 * DFEAT + lane]);
            float u6 = __half2float(xh[(size_t)p6 * DFEAT + lane]);
            float u7 = __half2float(xh[(size_t)p7 * DFEAT + lane]);
            aa += ((u0 + u1) + (u2 + u3)) + ((u4 + u5) + (u6 + u7));
        }
        for (; ja < da; ++ja)
            aa += __half2float(xh[(size_t)epa[ja] * DFEAT + lane]);
        // row b remainder
        int jb = j;
        for (; jb + 8 <= db; jb += 8) {
            int p0 = epb[jb + 0], p1 = epb[jb + 1], p2 = epb[jb + 2], p3 = epb[jb + 3];
            int p4 = epb[jb + 4], p5 = epb[jb + 5], p6 = epb[jb + 6], p7 = epb[jb + 7];
            float g0 = __half2float(xh[(size_t)p0 * DFEAT + lane]);
            float g1 = __half2float(xh[(size_t)p1 * DFEAT + lane]);
            float g2 = __half2float(xh[(size_t)p2 * DFEAT + lane]);
            float g3 = __half2float(xh[(size_t)p3 * DFEAT + lane]);
            float g4 = __half2float(xh[(size_t)p4 * DFEAT + lane]);
            float g5 = __half2float(xh[(size_t)p5 * DFEAT + lane]);
            float g6 = __half2float(xh[(size_t)p6 * DFEAT + lane]);
            float g7 = __half2float(xh[(size_t)p7 * DFEAT + lane]);
            ab += ((g0 + g1) + (g2 + g3)) + ((g4 + g5) + (g6 + g7));
        }
        for (; jb < db; ++jb)
            ab += __half2float(xh[(size_t)epb[jb] * DFEAT + lane]);

        aq[qa] = aa * rsqrtf((float)max(da, 1));   // norm_dst
        aq[qb] = ab * rsqrtf((float)max(db, 1));
    }

    // ---- in-wave GEMM tail, W read shared by 4 rows
    float yo0 = 0.f, yo1 = 0.f, yo2 = 0.f, yo3 = 0.f;
    int ai0 = __float_as_int(aq[0]);
    int ai1 = __float_as_int(aq[1]);
    int ai2 = __float_as_int(aq[2]);
    int ai3 = __float_as_int(aq[3]);
    #pragma unroll 8
    for (int k = 0; k < DFEAT; ++k) {
        float wk = Wl[k * DFEAT + lane];     // conflict-free, 1 read / 4 rows
        yo0 = fmaf(__int_as_float(__builtin_amdgcn_readlane(ai0, k)), wk, yo0);
        yo1 = fmaf(__int_as_float(__builtin_amdgcn_readlane(ai1, k)), wk, yo1);
        yo2 = fmaf(__int_as_float(__builtin_amdgcn_readlane(ai2, k)), wk, yo2);
        yo3 = fmaf(__int_as_float(__builtin_amdgcn_readlane(ai3, k)), wk, yo3);
    }

    float yq[4] = {yo0, yo1, yo2, yo3};
    float ps = 0.f, pq = 0.f;                // column (=lane) partial stats
    #pragma unroll
    for (int q = 0; q < 4; ++q) {
        int r = r0 + q;
        if (r < N) {
            float yv = bv + yq[q];
            y[(size_t)r * DFEAT + lane] = yv;
            ps += yv;
            pq = fmaf(yv, yv, pq);
        }
    }

    red_s[w][lane] = ps;
    red_q[w][lane] = pq;
    __syncthreads();
    if (w == 0) {
        float s = red_s[0][lane] + red_s[1][lane] + red_s[2][lane] + red_s[3][lane];
        float q2 = red_q[0][lane] + red_q[1][lane] + red_q[2][lane] + red_q[3][lane];
        float* p = partial + (size_t)blockIdx.x * 128;
        p[lane] = s;
        p[64 + lane] = q2;
    }
}

// ---------------- BN stats finalize: contiguous spans, 4-way ILP ----------------
__global__ void bnstat2_kernel(const float* __restrict__ partial,
                               float* __restrict__ sums, int G) {
    int j = threadIdx.x;                      // 0..127 (sums||sumsq column)
    int span = (G + (int)gridDim.x - 1) / (int)gridDim.x;
    int g0 = blockIdx.x * span;
    int g1 = min(G, g0 + span);
    float s0 = 0.f, s1 = 0.f, s2 = 0.f, s3 = 0.f;
    int g = g0;
    for (; g + 4 <= g1; g += 4) {
        s0 += partial[(size_t)(g + 0) * 128 + j];
        s1 += partial[(size_t)(g + 1) * 128 + j];
        s2 += partial[(size_t)(g + 2) * 128 + j];
        s3 += partial[(size_t)(g + 3) * 128 + j];
    }
    for (; g < g1; ++g) s0 += partial[(size_t)g * 128 + j];
    float s = (s0 + s1) + (s2 + s3);
    atomicAdd(&sums[j], s);                   // sums||sumsq contiguous
}

// ---------------- BN (batch stats) + ReLU + residual, float4, in place on y ----------------
__global__ void bn_relu_res_kernel(const float* __restrict__ x,
                                   const float* __restrict__ sums,
                                   const float* __restrict__ sumsq,
                                   const float* __restrict__ gamma,
                                   const float* __restrict__ beta,
                                   float* __restrict__ y, int n4, float inv_n) {
    int i = blockIdx.x * blockDim.x + threadIdx.x;   // float4 index
    if (i < n4) {
        int c0 = (i << 2) & (DFEAT - 1);
        float4 yv = ((const float4*)y)[i];
        float4 xv = ((const float4*)x)[i];
        float o[4] = {yv.x, yv.y, yv.z, yv.w};
        float xi[4] = {xv.x, xv.y, xv.z, xv.w};
        #pragma unroll
        for (int k = 0; k < 4; ++k) {
            int c = c0 + k;
            float mean = sums[c] * inv_n;
            float var = sumsq[c] * inv_n - mean * mean;
            float inv = rsqrtf(var + EPSBN);
            float v = (o[k] - mean) * inv * gamma[c] + beta[c];
            o[k] = xi[k] + fmaxf(v, 0.f);
        }
        ((float4*)y)[i] = make_float4(o[0], o[1], o[2], o[3]);
    }
}

extern "C" void kernel_launch(void* const* d_in, const int* in_sizes, int n_in,
                              void* d_out, int out_size, void* d_ws, size_t ws_size,
                              hipStream_t stream) {
    const float* x     = (const float*)d_in[0];
    const int*   src   = (const int*)d_in[1];
    const int*   dst   = (const int*)d_in[2];
    const float* W     = (const float*)d_in[3];
    const float* bvec  = (const float*)d_in[4];
    const float* gamma = (const float*)d_in[5];
    const float* beta  = (const float*)d_in[6];
    float* out = (float*)d_out;   // y, written once by fused spmm+gemm

    const int n_nodes = in_sizes[0] / DFEAT;
    const int E = in_sizes[1];
    const int NB = (n_nodes + SCB - 1) / SCB;           // scan3 blocks (49)
    const int C = (E + CHUNK - 1) >> CHUNK_LG;          // edge chunks (49)
    const int P = (n_nodes + RNG - 1) / RNG;            // node partitions (13)
    const int N_pad = P * RNG;                          // 106496 (div by 4)
    const size_t tbl = (size_t)C * N_pad;               // 5.2MB u8 cnt table

    // ws: epack (E int, 6.4MB) | x16 (N*64 fp16, 12.8MB) | lrank (E u8, 1.6MB) |
    //     cnt (C*N_pad u8, 5.2MB) | deg_out N | sums 64 | sumsq 64 | deg_in N |
    //     row_start N+1 | bsum 512     (total ~27.3MB)
    // partial aliases cnt (dead after fill): grid_sg*512B = 3.2MB <= 5.2MB.
    char* wsb = (char*)d_ws;
    int* epack            = (int*)wsb;
    unsigned short* x16   = (unsigned short*)(wsb + (size_t)E * 4);
    unsigned char* lrank  = (unsigned char*)((char*)x16 + (size_t)n_nodes * DFEAT * 2);
    size_t lrank_bytes    = ((size_t)E + 15) & ~(size_t)15;
    unsigned char* cnt    = lrank + lrank_bytes;
    int*  deg_out_i  = (int*)(cnt + tbl);
    float* sums      = (float*)(deg_out_i + n_nodes);
    float* sumsq     = sums + DFEAT;
    int*  deg_in_i   = (int*)(sumsq + DFEAT);
    int*  row_start  = deg_in_i + n_nodes;
    int*  bsum       = row_start + n_nodes + 1;         // 100 used, 512 reserved
    float* partial   = (float*)cnt;

    // zero: deg_out + sums + sumsq (contiguous; bnstat2 atomic-accumulates).
    hipMemsetAsync(deg_out_i, 0, ((size_t)n_nodes + 2 * DFEAT) * sizeof(int), stream);

    hist2d_kernel<<<dim3(P, C), 256, 0, stream>>>(src, dst, lrank, cnt, deg_out_i,
                                                  E, n_nodes, N_pad);

    int n4 = n_nodes * DFEAT / 4;
    int ngroups = (n_nodes + 3) / 4;                    // u32 groups of 4 nodes
    int NCS = (ngroups + 255) / 256;                    // colscan blocks (100)
    int NXB = (n4 + 255) / 256;                         // xcast blocks (1563)
    mid_kernel<<<NCS + NXB, 256, 0, stream>>>(
        (unsigned int*)cnt, deg_in_i, bsum, n_nodes, N_pad / 4, C, NCS,
        x, deg_out_i, x16, n4);

    scan3_kernel<<<NB, 256, 0, stream>>>(deg_in_i, bsum, row_start, n_nodes, E);

    int nvec = E >> 2;
    fill_kernel<<<(nvec + 255) / 256, 256, 0, stream>>>(src, dst, lrank, cnt,
                                                        row_start, epack, E, N_pad);

    int grid_sg = (n_nodes + 15) / 16;
    spmm_gemm_kernel<<<grid_sg, 256, 0, stream>>>(x16, row_start, epack,
                                                  W, bvec, out, partial, n_nodes);

    bnstat2_kernel<<<64, 128, 0, stream>>>(partial, sums, grid_sg);

    bn_relu_res_kernel<<<(n4 + 255) / 256, 256, 0, stream>>>(
        x, sums, sumsq, gamma, beta, out, n4, 1.0f / (float)n_nodes);
}

// Round 18
// 265.550 us; speedup vs baseline: 1.4716x; 1.0572x over previous
//
#include <hip/hip_runtime.h>
#include <hip/hip_fp16.h>

#define DFEAT 64
#define EPSBN 1e-5f
#define SCB 2048      // nodes per scan3 block (256 threads x 8)
#define CHUNK_LG 15
#define CHUNK (1 << CHUNK_LG)   // 32768 edges per chunk
#define RNG 8192      // nodes per partition (one packed 32KB LDS histogram)

// ---------------- LDS-privatized PACKED dual histogram + chunk-local rank ----------------
// one 32KB LDS array: low16 = dst count, high16 = src count. lrank/cnt are u8.
// Grid is (P, C): the 13 partition-blocks of one chunk dispatch ADJACENTLY ->
// the chunk is read once into L2 and shared. 32KB keeps 5 blocks/CU.
__global__ __launch_bounds__(256) void hist2d_kernel(
        const int* __restrict__ src, const int* __restrict__ dst,
        unsigned char* __restrict__ lrank, unsigned char* __restrict__ cnt,
        int* __restrict__ deg_out, int E, int N, int N_pad) {
    __shared__ int h[RNG];
    int tid = threadIdx.x;
    int c = blockIdx.y, p = blockIdx.x;
    int nbeg = p * RNG;
    for (int i = tid; i < RNG; i += 256) h[i] = 0;
    __syncthreads();

    int ebeg = c << CHUNK_LG;
    int eend = min(ebeg + CHUNK, E);
    int nvec = (eend - ebeg) >> 2;              // full int4 groups
    const int4* src4 = (const int4*)(src + ebeg);
    const int4* dst4 = (const int4*)(dst + ebeg);

    int i = tid;
    int4 s4 = make_int4(0, 0, 0, 0), d4 = s4;
    if (i < nvec) { s4 = src4[i]; d4 = dst4[i]; }
    while (i < nvec) {
        int inext = i + 256;
        int4 sn = make_int4(0, 0, 0, 0), dn = sn;
        if (inext < nvec) { sn = src4[inext]; dn = dst4[inext]; }   // prefetch
        int e = ebeg + (i << 2);
        {
            unsigned int so, dof;
            so = (unsigned int)(s4.x - nbeg); if (so < RNG) atomicAdd(&h[so], 0x10000);
            so = (unsigned int)(s4.y - nbeg); if (so < RNG) atomicAdd(&h[so], 0x10000);
            so = (unsigned int)(s4.z - nbeg); if (so < RNG) atomicAdd(&h[so], 0x10000);
            so = (unsigned int)(s4.w - nbeg); if (so < RNG) atomicAdd(&h[so], 0x10000);
            dof = (unsigned int)(d4.x - nbeg);
            if (dof < RNG) lrank[e + 0] = (unsigned char)(atomicAdd(&h[dof], 1) & 0xff);
            dof = (unsigned int)(d4.y - nbeg);
            if (dof < RNG) lrank[e + 1] = (unsigned char)(atomicAdd(&h[dof], 1) & 0xff);
            dof = (unsigned int)(d4.z - nbeg);
            if (dof < RNG) lrank[e + 2] = (unsigned char)(atomicAdd(&h[dof], 1) & 0xff);
            dof = (unsigned int)(d4.w - nbeg);
            if (dof < RNG) lrank[e + 3] = (unsigned char)(atomicAdd(&h[dof], 1) & 0xff);
        }
        s4 = sn; d4 = dn; i = inext;
    }
    for (int e = ebeg + (nvec << 2) + tid; e < eend; e += 256) {
        unsigned int so = (unsigned int)(src[e] - nbeg);
        unsigned int dof = (unsigned int)(dst[e] - nbeg);
        if (so < RNG) atomicAdd(&h[so], 0x10000);
        if (dof < RNG) lrank[e] = (unsigned char)(atomicAdd(&h[dof], 1) & 0xff);
    }
    __syncthreads();

    for (int i2 = tid; i2 < RNG; i2 += 256) {
        int n = nbeg + i2;
        if (n < N) {
            unsigned int v = (unsigned int)h[i2];
            unsigned int vo = v >> 16;
            if (vo) atomicAdd(&deg_out[n], (int)vo);   // contiguous lanes -> batched
            cnt[(size_t)c * N_pad + n] = (unsigned char)(v & 0xffu);
        }
    }
}

// ---------------- fused colscan + xcast (both depend only on hist2d) ----------------
__global__ __launch_bounds__(256) void mid_kernel(
        unsigned int* __restrict__ cnt4, int* __restrict__ deg_in,
        int* __restrict__ bsum, int N, int N_pad4, int C, int NCS,
        const float* __restrict__ x, const int* __restrict__ deg_out,
        unsigned short* __restrict__ x16, int n4) {
    __shared__ int red[256];
    int t = threadIdx.x;
    int b = blockIdx.x;
    if (b >= NCS) {
        // ---- xcast part ----
        int i = (b - NCS) * 256 + t;            // float4 index
        if (i < n4) {
            float coef = rsqrtf((float)max(deg_out[i >> 4], 1));   // 16 f4/row
            float4 v = ((const float4*)x)[i];
            __half2 lo = __floats2half2_rn(v.x * coef, v.y * coef);
            __half2 hi = __floats2half2_rn(v.z * coef, v.w * coef);
            ((__half2*)x16)[2 * i]     = lo;
            ((__half2*)x16)[2 * i + 1] = hi;
        }
        return;
    }
    // ---- colscan part ----
    int g = b * 256 + t;                        // u32 group index (node n0 = 4g)
    int n0 = g << 2;
    int r0 = 0, r1 = 0, r2 = 0, r3 = 0;
    if (n0 < N) {
        for (int c = 0; c < C; ++c) {
            size_t idx = (size_t)c * N_pad4 + g;
            unsigned int v = cnt4[idx];
            cnt4[idx] = (unsigned int)r0 | ((unsigned int)r1 << 8) |
                        ((unsigned int)r2 << 16) | ((unsigned int)r3 << 24);
            r0 += (int)(v & 0xffu);
            r1 += (int)((v >> 8) & 0xffu);
            r2 += (int)((v >> 16) & 0xffu);
            r3 += (int)(v >> 24);
        }
    }
    int tot = 0;
    if (n0     < N) { deg_in[n0]     = r0; tot += r0; }
    if (n0 + 1 < N) { deg_in[n0 + 1] = r1; tot += r1; }
    if (n0 + 2 < N) { deg_in[n0 + 2] = r2; tot += r2; }
    if (n0 + 3 < N) { deg_in[n0 + 3] = r3; tot += r3; }
    red[t] = tot;
    __syncthreads();
    for (int d = 128; d > 0; d >>= 1) {
        if (t < d) red[t] += red[t + d];
        __syncthreads();
    }
    if (t == 0) bsum[b] = red[0];
}

// ---------------- full exclusive scan -> row_start (scan2 folded in) ----------------
__global__ void scan3_kernel(const int* __restrict__ deg, const int* __restrict__ bsum,
                             int* __restrict__ row_start, int N, int E) {
    __shared__ int sc[256];
    __shared__ int base_sh;
    int t = threadIdx.x;
    int limit = blockIdx.x * (SCB / 1024);   // colscan blocks preceding this block
    if (t < 64) {
        int s = 0;
        for (int j = t; j < limit; j += 64) s += bsum[j];
        #pragma unroll
        for (int off = 32; off > 0; off >>= 1) s += __shfl_down(s, off);
        if (t == 0) base_sh = s;
    }
    int base = blockIdx.x * SCB + t * 8;
    int v[8], ex[8];
    int s = 0;
    #pragma unroll
    for (int j = 0; j < 8; ++j) {
        int idx = base + j;
        v[j] = (idx < N) ? deg[idx] : 0;
        ex[j] = s;
        s += v[j];
    }
    sc[t] = s;
    __syncthreads();                          // also orders base_sh write
    for (int d = 1; d < 256; d <<= 1) {
        int vv = (t >= d) ? sc[t - d] : 0;
        __syncthreads();
        sc[t] += vv;
        __syncthreads();
    }
    int toff = sc[t] - s + base_sh;
    #pragma unroll
    for (int j = 0; j < 8; ++j) {
        int idx = base + j;
        if (idx < N) row_start[idx] = toff + ex[j];
    }
    if (blockIdx.x == 0 && t == 0) row_start[N] = E;
}

// ---------------- place edges, 4/thread: slot = row_start[d] + pref + lrank ----------------
__global__ __launch_bounds__(256) void fill_kernel(
        const int* __restrict__ src, const int* __restrict__ dst,
        const unsigned char* __restrict__ lrank,
        const unsigned char* __restrict__ cnt,
        const int* __restrict__ row_start,
        int* __restrict__ epack, int E, int N_pad) {
    int i = blockIdx.x * 256 + threadIdx.x;   // int4 group index
    int nvec = E >> 2;
    if (i < nvec) {
        int4 s4 = ((const int4*)src)[i];
        int4 d4 = ((const int4*)dst)[i];
        uchar4 r4 = ((const uchar4*)lrank)[i];
        size_t cb = (size_t)((i << 2) >> CHUNK_LG) * N_pad;
        epack[row_start[d4.x] + (int)cnt[cb + d4.x] + (int)r4.x] = s4.x;
        epack[row_start[d4.y] + (int)cnt[cb + d4.y] + (int)r4.y] = s4.y;
        epack[row_start[d4.z] + (int)cnt[cb + d4.z] + (int)r4.z] = s4.z;
        epack[row_start[d4.w] + (int)cnt[cb + d4.w] + (int)r4.w] = s4.w;
    }
    int e = (nvec << 2) + i;                  // <=3 tail edges
    if (e < E && i < 4) {
        int d = dst[e];
        size_t cb = (size_t)(e >> CHUNK_LG) * N_pad;
        epack[row_start[d] + (int)cnt[cb + d] + (int)lrank[e]] = src[e];
    }
}

// ---------------- fused SpMM + GEMM + BN partials: 4 rows per wave ----------------
// r13/r15/r17 all tried to add source-level ILP to this loop (within-row
// pipelining, cross-row conditional arrays, pairwise lockstep) and ALL
// regressed: +VALU on the chain, scratch spill (WRITE 28->337MB), or broken
// compiler scheduling (+15us). The serial form below is the measured optimum
// -- wave-level TLP (22 waves/CU) supplies the memory-level parallelism.
// Edge loop: wave-uniform s_load walk of epack (src only); gather is a 2B
// fp16 load of PREMULTIPLIED x16; per-edge vector work = v_cvt_f32_f16 + add.
__global__ __launch_bounds__(256, 8) void spmm_gemm_kernel(
        const unsigned short* __restrict__ x16, const int* __restrict__ row_start,
        const int* __restrict__ epack, const float* __restrict__ W,
        const float* __restrict__ bvec, float* __restrict__ y,
        float* __restrict__ partial, int N) {
    __shared__ float Wl[DFEAT * DFEAT];
    __shared__ float red_s[4][DFEAT];
    __shared__ float red_q[4][DFEAT];
    int tid = threadIdx.x;
    {
        const float4* W4 = (const float4*)W;
        float4* Wl4 = (float4*)Wl;
        #pragma unroll
        for (int j = 0; j < 4; ++j) Wl4[tid + 256 * j] = W4[tid + 256 * j];
    }
    __syncthreads();

    int lane = tid & 63;
    int w = tid >> 6;
    int r0 = blockIdx.x * 16 + w * 4;
    float bv = bvec[lane];
    const __half* xh = (const __half*)x16;

    float acc[4];
    #pragma unroll
    for (int q = 0; q < 4; ++q) {
        float a = 0.f;
        int r = r0 + q;
        if (r < N) {
            int beg = __builtin_amdgcn_readfirstlane(row_start[r]);
            int end = __builtin_amdgcn_readfirstlane(row_start[r + 1]);
            int deg = end - beg;
            const int* ep = epack + beg;        // uniform pointer -> s_load walk
            int j = 0;
            for (; j + 8 <= deg; j += 8) {
                int p0 = ep[j + 0], p1 = ep[j + 1], p2 = ep[j + 2], p3 = ep[j + 3];
                int p4 = ep[j + 4], p5 = ep[j + 5], p6 = ep[j + 6], p7 = ep[j + 7];
                float v0 = __half2float(xh[(size_t)p0 * DFEAT + lane]);
                float v1 = __half2float(xh[(size_t)p1 * DFEAT + lane]);
                float v2 = __half2float(xh[(size_t)p2 * DFEAT + lane]);
                float v3 = __half2float(xh[(size_t)p3 * DFEAT + lane]);
                float v4 = __half2float(xh[(size_t)p4 * DFEAT + lane]);
                float v5 = __half2float(xh[(size_t)p5 * DFEAT + lane]);
                float v6 = __half2float(xh[(size_t)p6 * DFEAT + lane]);
                float v7 = __half2float(xh[(size_t)p7 * DFEAT + lane]);
                a += ((v0 + v1) + (v2 + v3)) + ((v4 + v5) + (v6 + v7));
            }
            for (; j < deg; ++j) {
                int p = ep[j];
                a += __half2float(xh[(size_t)p * DFEAT + lane]);
            }
            a *= rsqrtf((float)max(deg, 1));   // norm_dst: a = agg[r][lane]
        }
        acc[q] = a;
    }

    // ---- in-wave GEMM tail, W read shared by 4 rows
    float yo0 = 0.f, yo1 = 0.f, yo2 = 0.f, yo3 = 0.f;
    int ai0 = __float_as_int(acc[0]);
    int ai1 = __float_as_int(acc[1]);
    int ai2 = __float_as_int(acc[2]);
    int ai3 = __float_as_int(acc[3]);
    #pragma unroll 8
    for (int k = 0; k < DFEAT; ++k) {
        float wk = Wl[k * DFEAT + lane];     // conflict-free, 1 read / 4 rows
        yo0 = fmaf(__int_as_float(__builtin_amdgcn_readlane(ai0, k)), wk, yo0);
        yo1 = fmaf(__int_as_float(__builtin_amdgcn_readlane(ai1, k)), wk, yo1);
        yo2 = fmaf(__int_as_float(__builtin_amdgcn_readlane(ai2, k)), wk, yo2);
        yo3 = fmaf(__int_as_float(__builtin_amdgcn_readlane(ai3, k)), wk, yo3);
    }

    float yq[4] = {yo0, yo1, yo2, yo3};
    float ps = 0.f, pq = 0.f;                // column (=lane) partial stats
    #pragma unroll
    for (int q = 0; q < 4; ++q) {
        int r = r0 + q;
        if (r < N) {
            float yv = bv + yq[q];
            y[(size_t)r * DFEAT + lane] = yv;
            ps += yv;
            pq = fmaf(yv, yv, pq);
        }
    }

    red_s[w][lane] = ps;
    red_q[w][lane] = pq;
    __syncthreads();
    if (w == 0) {
        float s = red_s[0][lane] + red_s[1][lane] + red_s[2][lane] + red_s[3][lane];
        float q2 = red_q[0][lane] + red_q[1][lane] + red_q[2][lane] + red_q[3][lane];
        float* p = partial + (size_t)blockIdx.x * 128;
        p[lane] = s;
        p[64 + lane] = q2;
    }
}

// ---------------- BN stats finalize: contiguous spans, 4-way ILP ----------------
__global__ void bnstat2_kernel(const float* __restrict__ partial,
                               float* __restrict__ sums, int G) {
    int j = threadIdx.x;                      // 0..127 (sums||sumsq column)
    int span = (G + (int)gridDim.x - 1) / (int)gridDim.x;
    int g0 = blockIdx.x * span;
    int g1 = min(G, g0 + span);
    float s0 = 0.f, s1 = 0.f, s2 = 0.f, s3 = 0.f;
    int g = g0;
    for (; g + 4 <= g1; g += 4) {
        s0 += partial[(size_t)(g + 0) * 128 + j];
        s1 += partial[(size_t)(g + 1) * 128 + j];
        s2 += partial[(size_t)(g + 2) * 128 + j];
        s3 += partial[(size_t)(g + 3) * 128 + j];
    }
    for (; g < g1; ++g) s0 += partial[(size_t)g * 128 + j];
    float s = (s0 + s1) + (s2 + s3);
    atomicAdd(&sums[j], s);                   // sums||sumsq contiguous
}

// ---------------- BN (batch stats) + ReLU + residual, float4, in place on y ----------------
__global__ void bn_relu_res_kernel(const float* __restrict__ x,
                                   const float* __restrict__ sums,
                                   const float* __restrict__ sumsq,
                                   const float* __restrict__ gamma,
                                   const float* __restrict__ beta,
                                   float* __restrict__ y, int n4, float inv_n) {
    int i = blockIdx.x * blockDim.x + threadIdx.x;   // float4 index
    if (i < n4) {
        int c0 = (i << 2) & (DFEAT - 1);
        float4 yv = ((const float4*)y)[i];
        float4 xv = ((const float4*)x)[i];
        float o[4] = {yv.x, yv.y, yv.z, yv.w};
        float xi[4] = {xv.x, xv.y, xv.z, xv.w};
        #pragma unroll
        for (int k = 0; k < 4; ++k) {
            int c = c0 + k;
            float mean = sums[c] * inv_n;
            float var = sumsq[c] * inv_n - mean * mean;
            float inv = rsqrtf(var + EPSBN);
            float v = (o[k] - mean) * inv * gamma[c] + beta[c];
            o[k] = xi[k] + fmaxf(v, 0.f);
        }
        ((float4*)y)[i] = make_float4(o[0], o[1], o[2], o[3]);
    }
}

extern "C" void kernel_launch(void* const* d_in, const int* in_sizes, int n_in,
                              void* d_out, int out_size, void* d_ws, size_t ws_size,
                              hipStream_t stream) {
    const float* x     = (const float*)d_in[0];
    const int*   src   = (const int*)d_in[1];
    const int*   dst   = (const int*)d_in[2];
    const float* W     = (const float*)d_in[3];
    const float* bvec  = (const float*)d_in[4];
    const float* gamma = (const float*)d_in[5];
    const float* beta  = (const float*)d_in[6];
    float* out = (float*)d_out;   // y, written once by fused spmm+gemm

    const int n_nodes = in_sizes[0] / DFEAT;
    const int E = in_sizes[1];
    const int NB = (n_nodes + SCB - 1) / SCB;           // scan3 blocks (49)
    const int C = (E + CHUNK - 1) >> CHUNK_LG;          // edge chunks (49)
    const int P = (n_nodes + RNG - 1) / RNG;            // node partitions (13)
    const int N_pad = P * RNG;                          // 106496 (div by 4)
    const size_t tbl = (size_t)C * N_pad;               // 5.2MB u8 cnt table

    // ws: epack (E int, 6.4MB) | x16 (N*64 fp16, 12.8MB) | lrank (E u8, 1.6MB) |
    //     cnt (C*N_pad u8, 5.2MB) | deg_out N | sums 64 | sumsq 64 | deg_in N |
    //     row_start N+1 | bsum 512     (total ~27.3MB)
    // partial aliases cnt (dead after fill): grid_sg*512B = 3.2MB <= 5.2MB.
    char* wsb = (char*)d_ws;
    int* epack            = (int*)wsb;
    unsigned short* x16   = (unsigned short*)(wsb + (size_t)E * 4);
    unsigned char* lrank  = (unsigned char*)((char*)x16 + (size_t)n_nodes * DFEAT * 2);
    size_t lrank_bytes    = ((size_t)E + 15) & ~(size_t)15;
    unsigned char* cnt    = lrank + lrank_bytes;
    int*  deg_out_i  = (int*)(cnt + tbl);
    float* sums      = (float*)(deg_out_i + n_nodes);
    float* sumsq     = sums + DFEAT;
    int*  deg_in_i   = (int*)(sumsq + DFEAT);
    int*  row_start  = deg_in_i + n_nodes;
    int*  bsum       = row_start + n_nodes + 1;         // 100 used, 512 reserved
    float* partial   = (float*)cnt;

    // zero: deg_out + sums + sumsq (contiguous; bnstat2 atomic-accumulates).
    hipMemsetAsync(deg_out_i, 0, ((size_t)n_nodes + 2 * DFEAT) * sizeof(int), stream);

    hist2d_kernel<<<dim3(P, C), 256, 0, stream>>>(src, dst, lrank, cnt, deg_out_i,
                                                  E, n_nodes, N_pad);

    int n4 = n_nodes * DFEAT / 4;
    int ngroups = (n_nodes + 3) / 4;                    // u32 groups of 4 nodes
    int NCS = (ngroups + 255) / 256;                    // colscan blocks (100)
    int NXB = (n4 + 255) / 256;                         // xcast blocks (1563)
    mid_kernel<<<NCS + NXB, 256, 0, stream>>>(
        (unsigned int*)cnt, deg_in_i, bsum, n_nodes, N_pad / 4, C, NCS,
        x, deg_out_i, x16, n4);

    scan3_kernel<<<NB, 256, 0, stream>>>(deg_in_i, bsum, row_start, n_nodes, E);

    int nvec = E >> 2;
    fill_kernel<<<(nvec + 255) / 256, 256, 0, stream>>>(src, dst, lrank, cnt,
                                                        row_start, epack, E, N_pad);

    int grid_sg = (n_nodes + 15) / 16;
    spmm_gemm_kernel<<<grid_sg, 256, 0, stream>>>(x16, row_start, epack,
                                                  W, bvec, out, partial, n_nodes);

    bnstat2_kernel<<<64, 128, 0, stream>>>(partial, sums, grid_sg);

    bn_relu_res_kernel<<<(n4 + 255) / 256, 256, 0, stream>>>(
        x, sums, sumsq, gamma, beta, out, n4, 1.0f / (float)n_nodes);
}